// Round 9
// baseline (475.583 us; speedup 1.0000x reference)
//
#include <hip/hip_runtime.h>
#include <stdint.h>

#define T_STEPS 512
#define CELLS   4096            // 64*64
#define EPB     32              // envs per block (2 per active lane, lanes mirrored x4)
#define WPE     256             // packed world words per env (16 cells/word)
#define WPAD    257             // world LDS stride; word 256 = OOB sentinel (0)
#define ASTRIDE 130             // action LDS stride (129 words used + slack)
#define SSTRIDE 66              // traj s-buf stride: 32 steps * 2 + 2
#define RSTRIDE 33              // traj r-buf stride
#define CHUNK   32              // steps between coalesced flushes
#define NCHUNK  (T_STEPS / CHUNK)   // 16
#define KPC     (CHUNK / 4)         // 8 four-step k-iters per chunk

// ---- Kernel 1: pack world (float walls+goals) to 2-bit codes in d_ws ----
// code: 2 = goal (g==10, priority), 1 = wall (w==1 && !goal), 0 = free
__device__ __forceinline__ uint32_t code4(float4 w, float4 g) {
    uint32_t b0 = (g.x == 10.0f) ? 2u : ((w.x == 1.0f) ? 1u : 0u);
    uint32_t b1 = (g.y == 10.0f) ? 2u : ((w.y == 1.0f) ? 1u : 0u);
    uint32_t b2 = (g.z == 10.0f) ? 2u : ((w.z == 1.0f) ? 1u : 0u);
    uint32_t b3 = (g.w == 10.0f) ? 2u : ((w.w == 1.0f) ? 1u : 0u);
    return b0 | (b1 << 2) | (b2 << 4) | (b3 << 6);   // 4 cells x 2 bits
}

__global__ __launch_bounds__(64) void pack_kernel(
    const float* __restrict__ world, uint32_t* __restrict__ packed)
{
    const int b = blockIdx.x;
    const int t = threadIdx.x;
    const float* wbase = world + (size_t)b * (2 * CELLS);
    const float* gbase = wbase + CELLS;
    #pragma unroll
    for (int h = 0; h < 4; ++h) {
        const int w  = h * 64 + t;     // word index, 16 cells per word
        const int c0 = w * 16;
        uint32_t word = 0;
        #pragma unroll
        for (int j = 0; j < 4; ++j) {
            float4 wf = *(const float4*)(wbase + c0 + 4 * j);
            float4 gf = *(const float4*)(gbase + c0 + 4 * j);
            word |= code4(wf, gf) << (8 * j);
        }
        packed[(size_t)b * WPE + w] = word;
    }
}

// ---- Kernel 2: rollout, 2 envs per lane software-interleaved ----
__global__ __launch_bounds__(64) void rollout_kernel(
    const float* __restrict__ s0,
    const int*   __restrict__ act,
    const uint32_t* __restrict__ packed,
    float* __restrict__ out,
    int B)
{
    __shared__ uint32_t wlds[EPB * WPAD];      // 32896 B: 2-bit worlds
    __shared__ uint32_t alds[EPB * ASTRIDE];   // 16640 B: byte-packed actions
    __shared__ float    sbuf[EPB * SSTRIDE];   //  8448 B: 32-step s trajectory
    __shared__ float    rbuf[EPB * RSTRIDE];   //  4224 B: 32-step r trajectory

    const int tid = threadIdx.x;
    const int b0  = blockIdx.x * EPB;

    // stage 32 envs' packed worlds (32 KB) into padded LDS
    for (int ee = 0; ee < EPB; ++ee) {
        uint4 v = *(const uint4*)(packed + (size_t)(b0 + ee) * WPE + tid * 4);
        const int base = ee * WPAD + tid * 4;
        wlds[base]     = v.x;
        wlds[base + 1] = v.y;
        wlds[base + 2] = v.z;
        wlds[base + 3] = v.w;
    }
    if (tid < EPB) wlds[tid * WPAD + WPE] = 0u;   // OOB sentinel word = free
    // stage 32 envs' actions as bytes: word w = actions[4w..4w+3]
    for (int ee = 0; ee < EPB; ++ee) {
        const int4* ap = (const int4*)(act + (size_t)(b0 + ee) * T_STEPS);
        const int4 x = ap[2 * tid];
        const int4 y = ap[2 * tid + 1];
        const uint32_t w0 = (uint32_t)(x.x & 255) | ((uint32_t)(x.y & 255) << 8)
                          | ((uint32_t)(x.z & 255) << 16) | ((uint32_t)(x.w & 255) << 24);
        const uint32_t w1 = (uint32_t)(y.x & 255) | ((uint32_t)(y.y & 255) << 8)
                          | ((uint32_t)(y.z & 255) << 16) | ((uint32_t)(y.w & 255) << 24);
        const int base = ee * ASTRIDE + 2 * tid;
        alds[base]     = w0;
        alds[base + 1] = w1;
    }
    __syncthreads();

    float* const s_base = out;                                    // [B][513][2]
    float* const r_base = out + (size_t)B * (2 * (T_STEPS + 1));  // [B][513]

    if (tid < EPB) {   // t=0 outputs
        const float2 si = *(const float2*)(s0 + 2 * (size_t)(b0 + tid));
        *(float2*)(s_base + (size_t)(b0 + tid) * (2 * (T_STEPS + 1))) = si;
        r_base[(size_t)(b0 + tid) * (T_STEPS + 1)] = 0.0f;
    }

    // lane handles envs eA = 2*(tid&15), eB = eA+1 (mirrored x4 across wave;
    // duplicate same-value LDS writes are benign, LDS reads broadcast)
    const int eA = 2 * (tid & 15);
    const int eB = eA + 1;
    const float2 sA = *(const float2*)(s0 + 2 * (size_t)(b0 + eA));
    const float2 sB = *(const float2*)(s0 + 2 * (size_t)(b0 + eB));
    int rA = (int)sA.x, cA = (int)sA.y, pA = rA * 64 + cA;
    int rB = (int)sB.x, cB = (int)sB.y, pB = rB * 64 + cB;
    const uint32_t* myA = wlds + eA * WPAD;
    const uint32_t* myB = wlds + eB * WPAD;
    const uint32_t* actA = alds + eA * ASTRIDE;
    const uint32_t* actB = alds + eB * ASTRIDE;

    // semantics (verified R3-R8, absmax 0): idx in [-4096,-1] wraps (+4096,
    // single NumPy normalization); all other OOB -> fill(NaN) -> free cell.
    // word = ((q & 4095) >> 4) covers the single-wrap case; the range check
    // routes multi-wrap negatives and q > 4095 to the sentinel word (0).
    auto waddr = [](int q) -> int {
        const int w = (int)((((unsigned)q) >> 4) & 255u);   // (q & 4095) >> 4
        return ((unsigned)(q + CELLS) < 2u * CELLS) ? w : WPE;
    };

    uint32_t awA = actA[0];
    uint32_t awB = actB[0];
    for (int chunk = 0; chunk < NCHUNK; ++chunk) {
        for (int k = 0; k < KPC; ++k) {
            const int kk = chunk * KPC + k;
            const uint32_t awA_n = actA[kk + 1];
            const uint32_t awB_n = actB[kk + 1];
            const int aA[4] = {(int)(awA & 255), (int)((awA >> 8) & 255),
                               (int)((awA >> 16) & 255), (int)((awA >> 24) & 255)};
            const int aB[4] = {(int)(awB & 255), (int)((awB >> 8) & 255),
                               (int)((awB >> 16) & 255), (int)((awB >> 24) & 255)};
            #pragma unroll
            for (int jj = 0; jj < 2; ++jj) {    // 2-step round, A and B interleaved
                const int ls = k * 4 + jj * 2;  // local step within chunk
                const int uA0 = aA[2 * jj], uA1 = aA[2 * jj + 1];
                const int uB0 = aB[2 * jj], uB1 = aB[2 * jj + 1];
                const int dA0r = (uA0 == 1) ? -1 : ((uA0 == 2) ? 1 : 0);
                const int dA0c = (uA0 == 3) ? -1 : ((uA0 == 4) ? 1 : 0);
                const int dA1r = (uA1 == 1) ? -1 : ((uA1 == 2) ? 1 : 0);
                const int dA1c = (uA1 == 3) ? -1 : ((uA1 == 4) ? 1 : 0);
                const int dB0r = (uB0 == 1) ? -1 : ((uB0 == 2) ? 1 : 0);
                const int dB0c = (uB0 == 3) ? -1 : ((uB0 == 4) ? 1 : 0);
                const int dB1r = (uB1 == 1) ? -1 : ((uB1 == 2) ? 1 : 0);
                const int dB1c = (uB1 == 3) ? -1 : ((uB1 == 4) ? 1 : 0);
                const int eAd0 = dA0r * 64 + dA0c, eAd1 = dA1r * 64 + dA1c;
                const int eBd0 = dB0r * 64 + dB0c, eBd1 = dB1r * 64 + dB1c;
                // issue A probes, then B probes (independent chains)
                const int qA0 = pA + eAd0, qA10 = pA + eAd1, qA11 = qA0 + eAd1;
                const uint32_t wA0  = myA[waddr(qA0)];
                const uint32_t wA10 = myA[waddr(qA10)];
                const uint32_t wA11 = myA[waddr(qA11)];
                const int qB0 = pB + eBd0, qB10 = pB + eBd1, qB11 = qB0 + eBd1;
                const uint32_t wB0  = myB[waddr(qB0)];
                const uint32_t wB10 = myB[waddr(qB10)];
                const uint32_t wB11 = myB[waddr(qB11)];
                // resolve A (B's probes still in flight fill the wait)
                {
                    const int l0 = (int)((wA0 >> ((qA0 & 15) * 2)) & 3);
                    const bool hw0 = (l0 == 1);
                    const float rew0 = (l0 == 2) ? 1.0f : (hw0 ? -1.0f : -0.01f);
                    const int p0  = hw0 ? pA : qA0;
                    const int r0v = hw0 ? rA : rA + dA0r;
                    const int c0v = hw0 ? cA : cA + dA0c;
                    const uint32_t W1 = hw0 ? wA10 : wA11;
                    const int q1 = p0 + eAd1;
                    const int l1 = (int)((W1 >> ((q1 & 15) * 2)) & 3);
                    const bool hw1 = (l1 == 1);
                    const float rew1 = (l1 == 2) ? 1.0f : (hw1 ? -1.0f : -0.01f);
                    pA = hw1 ? p0 : q1;
                    rA = hw1 ? r0v : r0v + dA1r;
                    cA = hw1 ? c0v : c0v + dA1c;
                    *(float2*)(&sbuf[eA * SSTRIDE + 2 * ls]) =
                        make_float2((float)r0v, (float)c0v);
                    *(float2*)(&sbuf[eA * SSTRIDE + 2 * ls + 2]) =
                        make_float2((float)rA, (float)cA);
                    rbuf[eA * RSTRIDE + ls]     = rew0;
                    rbuf[eA * RSTRIDE + ls + 1] = rew1;
                }
                // resolve B
                {
                    const int l0 = (int)((wB0 >> ((qB0 & 15) * 2)) & 3);
                    const bool hw0 = (l0 == 1);
                    const float rew0 = (l0 == 2) ? 1.0f : (hw0 ? -1.0f : -0.01f);
                    const int p0  = hw0 ? pB : qB0;
                    const int r0v = hw0 ? rB : rB + dB0r;
                    const int c0v = hw0 ? cB : cB + dB0c;
                    const uint32_t W1 = hw0 ? wB10 : wB11;
                    const int q1 = p0 + eBd1;
                    const int l1 = (int)((W1 >> ((q1 & 15) * 2)) & 3);
                    const bool hw1 = (l1 == 1);
                    const float rew1 = (l1 == 2) ? 1.0f : (hw1 ? -1.0f : -0.01f);
                    pB = hw1 ? p0 : q1;
                    rB = hw1 ? r0v : r0v + dB1r;
                    cB = hw1 ? c0v : c0v + dB1c;
                    *(float2*)(&sbuf[eB * SSTRIDE + 2 * ls]) =
                        make_float2((float)r0v, (float)c0v);
                    *(float2*)(&sbuf[eB * SSTRIDE + 2 * ls + 2]) =
                        make_float2((float)rB, (float)cB);
                    rbuf[eB * RSTRIDE + ls]     = rew0;
                    rbuf[eB * RSTRIDE + ls + 1] = rew1;
                }
            }
            awA = awA_n;
            awB = awB_n;
        }
        __syncthreads();
        // ---- coalesced flush: 64 contiguous floats per env (s), 32 (r) ----
        for (int ee = 0; ee < EPB; ++ee) {
            const float v = sbuf[ee * SSTRIDE + tid];
            s_base[(size_t)(b0 + ee) * (2 * (T_STEPS + 1)) + chunk * 64 + 2 + tid] = v;
        }
        for (int ee = 0; ee < EPB; ee += 2) {
            const int e2 = ee + (tid >> 5);
            const int j  = tid & 31;
            const float v = rbuf[e2 * RSTRIDE + j];
            r_base[(size_t)(b0 + e2) * (T_STEPS + 1) + chunk * 32 + 1 + j] = v;
        }
        __syncthreads();
    }
}

extern "C" void kernel_launch(void* const* d_in, const int* in_sizes, int n_in,
                              void* d_out, int out_size, void* d_ws, size_t ws_size,
                              hipStream_t stream) {
    const float* s0    = (const float*)d_in[0];
    const int*   act   = (const int*)d_in[1];
    const float* world = (const float*)d_in[2];
    float*       out   = (float*)d_out;
    uint32_t*    packed = (uint32_t*)d_ws;     // needs B*256*4 = 8 MiB

    const int B = in_sizes[0] / 2;             // 8192

    pack_kernel<<<B, 64, 0, stream>>>(world, packed);
    rollout_kernel<<<B / EPB, 64, 0, stream>>>(s0, act, packed, out, B);
}

// Round 10
// 436.915 us; speedup vs baseline: 1.0885x; 1.0885x over previous
//
#include <hip/hip_runtime.h>
#include <stdint.h>

#define T_STEPS 512
#define CELLS   4096            // 64*64
#define EPB     32              // envs per block (1 per lane, lanes mirrored x2)
#define WPE     256             // packed world words per env (16 cells/word)
#define WPAD    257             // world LDS stride; word 256 = OOB sentinel (0)
#define ASTRIDE 130             // delta LDS stride (128 words used + slack)
#define SSTRIDE 66              // traj s-buf stride: 32 steps * 2 + 2
#define RSTRIDE 34              // traj r-buf stride (even -> float2 aligned)
#define CHUNK   32              // steps between coalesced flushes
#define NCHUNK  (T_STEPS / CHUNK)   // 16
#define KPC     (CHUNK / 4)         // 8 four-step k-iters per chunk

// ---- Kernel 1: pack world (float walls+goals) to 2-bit codes in d_ws ----
// code: 2 = goal (g==10, priority), 1 = wall (w==1 && !goal), 0 = free
__device__ __forceinline__ uint32_t code4(float4 w, float4 g) {
    uint32_t b0 = (g.x == 10.0f) ? 2u : ((w.x == 1.0f) ? 1u : 0u);
    uint32_t b1 = (g.y == 10.0f) ? 2u : ((w.y == 1.0f) ? 1u : 0u);
    uint32_t b2 = (g.z == 10.0f) ? 2u : ((w.z == 1.0f) ? 1u : 0u);
    uint32_t b3 = (g.w == 10.0f) ? 2u : ((w.w == 1.0f) ? 1u : 0u);
    return b0 | (b1 << 2) | (b2 << 4) | (b3 << 6);   // 4 cells x 2 bits
}

__global__ __launch_bounds__(64) void pack_kernel(
    const float* __restrict__ world, uint32_t* __restrict__ packed)
{
    const int b = blockIdx.x;
    const int t = threadIdx.x;
    const float* wbase = world + (size_t)b * (2 * CELLS);
    const float* gbase = wbase + CELLS;
    #pragma unroll
    for (int h = 0; h < 4; ++h) {
        const int w  = h * 64 + t;     // word index, 16 cells per word
        const int c0 = w * 16;
        uint32_t word = 0;
        #pragma unroll
        for (int j = 0; j < 4; ++j) {
            float4 wf = *(const float4*)(wbase + c0 + 4 * j);
            float4 gf = *(const float4*)(gbase + c0 + 4 * j);
            word |= code4(wf, gf) << (8 * j);
        }
        packed[(size_t)b * WPE + w] = word;
    }
}

// action -> flat delta e = dr*64 + dc, stored as int8
__device__ __forceinline__ int actdelta(int a) {
    return (a == 1) ? -64 : ((a == 2) ? 64 : ((a == 3) ? -1 : ((a == 4) ? 1 : 0)));
}

// ---- Kernel 2: lane-dense rollout, slimmed depth-2 speculation ----
__global__ __launch_bounds__(64) void rollout_kernel(
    const float* __restrict__ s0,
    const int*   __restrict__ act,
    const uint32_t* __restrict__ packed,
    float* __restrict__ out,
    int B)
{
    __shared__ uint32_t wlds[EPB * WPAD];      // 32896 B: 2-bit worlds
    __shared__ uint32_t alds[EPB * ASTRIDE];   // 16640 B: int8 per-step deltas
    __shared__ float    sbuf[EPB * SSTRIDE];   //  8448 B: 32-step s trajectory
    __shared__ float    rbuf[EPB * RSTRIDE];   //  4352 B: 32-step r trajectory
                                               // total 62336 B

    const int tid = threadIdx.x;
    const int b0  = blockIdx.x * EPB;

    // stage 32 envs' packed worlds (32 KB) into padded LDS
    for (int ee = 0; ee < EPB; ++ee) {
        uint4 v = *(const uint4*)(packed + (size_t)(b0 + ee) * WPE + tid * 4);
        const int base = ee * WPAD + tid * 4;
        wlds[base]     = v.x;
        wlds[base + 1] = v.y;
        wlds[base + 2] = v.z;
        wlds[base + 3] = v.w;
    }
    if (tid < EPB) wlds[tid * WPAD + WPE] = 0u;   // OOB sentinel word = free
    // stage 32 envs' actions as pre-decoded int8 flat deltas
    for (int ee = 0; ee < EPB; ++ee) {
        const int4* ap = (const int4*)(act + (size_t)(b0 + ee) * T_STEPS);
        const int4 x = ap[2 * tid];
        const int4 y = ap[2 * tid + 1];
        const uint32_t w0 = (uint32_t)(actdelta(x.x) & 255)
                          | ((uint32_t)(actdelta(x.y) & 255) << 8)
                          | ((uint32_t)(actdelta(x.z) & 255) << 16)
                          | ((uint32_t)(actdelta(x.w) & 255) << 24);
        const uint32_t w1 = (uint32_t)(actdelta(y.x) & 255)
                          | ((uint32_t)(actdelta(y.y) & 255) << 8)
                          | ((uint32_t)(actdelta(y.z) & 255) << 16)
                          | ((uint32_t)(actdelta(y.w) & 255) << 24);
        const int base = ee * ASTRIDE + 2 * tid;
        alds[base]     = w0;
        alds[base + 1] = w1;
    }
    __syncthreads();

    float* const s_base = out;                                    // [B][513][2]
    float* const r_base = out + (size_t)B * (2 * (T_STEPS + 1));  // [B][513]

    if (tid < EPB) {   // t=0 outputs
        const float2 si = *(const float2*)(s0 + 2 * (size_t)(b0 + tid));
        *(float2*)(s_base + (size_t)(b0 + tid) * (2 * (T_STEPS + 1))) = si;
        r_base[(size_t)(b0 + tid) * (T_STEPS + 1)] = 0.0f;
    }

    // env per lane: e = tid & 31 (lanes 32-63 mirror 0-31; same-address LDS
    // reads broadcast, duplicate same-value LDS writes are benign)
    const int e = tid & (EPB - 1);
    const float2 s = *(const float2*)(s0 + 2 * (size_t)(b0 + e));
    int c = (int)s.y;
    int p = ((int)s.x) * 64 + c;            // invariant: p == r*64 + c (exact,
                                            // holds for OOB coords too)
    const uint32_t* myw = wlds + e * WPAD;
    const uint32_t* myd = alds + e * ASTRIDE;

    // semantics (verified R3-R9, absmax 0): idx in [-4096,-1] wraps (+4096,
    // single NumPy normalization); all other OOB -> fill(NaN) -> free cell.
    // word = ((q & 4095) >> 4); range check routes other OOB to sentinel (0).
    auto waddr = [](int q) -> int {
        const int w = (int)((((unsigned)q) >> 4) & 255u);   // (q & 4095) >> 4
        return ((unsigned)(q + CELLS) < 2u * CELLS) ? w : WPE;
    };

    for (int chunk = 0; chunk < NCHUNK; ++chunk) {
        for (int k = 0; k < KPC; ++k) {
            const uint32_t aw = myd[chunk * KPC + k];
            // sign-extended int8 deltas for the 4 steps
            const int e0 = (int)(aw << 24) >> 24;
            const int e1 = (int)(aw << 16) >> 24;
            const int e2 = (int)(aw << 8) >> 24;
            const int e3 = (int)aw >> 24;
            const int es[4] = {e0, e1, e2, e3};
            #pragma unroll
            for (int jj = 0; jj < 2; ++jj) {    // two speculative 2-step rounds
                const int ls = k * 4 + jj * 2;  // local step within chunk
                const int ea = es[2 * jj];
                const int eb = es[2 * jj + 1];
                const int dca = ea * (ea & 1);  // col part: ±1 -> ±1, else 0
                const int dcb = eb * (eb & 1);
                // speculative probes: step t from p; step t+1 from {p, p+ea}
                const int q0  = p + ea;
                const int q10 = p + eb;
                const int q11 = q0 + eb;
                const uint32_t w0  = myw[waddr(q0)];
                const uint32_t w10 = myw[waddr(q10)];
                const uint32_t w11 = myw[waddr(q11)];
                // resolve step t (identical to verified R8 logic)
                const int l0 = (int)((w0 >> ((q0 & 15) << 1)) & 3);
                const bool hw0 = (l0 == 1);
                const float rew0 = (l0 == 2) ? 1.0f : (hw0 ? -1.0f : -0.01f);
                const int p0 = hw0 ? p : q0;
                const int c0 = hw0 ? c : c + dca;
                // resolve step t+1 from the matching speculative read
                const uint32_t W1 = hw0 ? w10 : w11;
                const int q1 = p0 + eb;
                const int l1 = (int)((W1 >> ((q1 & 15) << 1)) & 3);
                const bool hw1 = (l1 == 1);
                const float rew1 = (l1 == 2) ? 1.0f : (hw1 ? -1.0f : -0.01f);
                p = hw1 ? p0 : q1;
                c = hw1 ? c0 : c0 + dcb;
                // r recovered exactly from the invariant (p-c is 64*r)
                const int r0i = (p0 - c0) >> 6;
                const int rfi = (p - c) >> 6;
                *(float2*)(&sbuf[e * SSTRIDE + 2 * ls]) =
                    make_float2((float)r0i, (float)c0);
                *(float2*)(&sbuf[e * SSTRIDE + 2 * ls + 2]) =
                    make_float2((float)rfi, (float)c);
                *(float2*)(&rbuf[e * RSTRIDE + ls]) = make_float2(rew0, rew1);
            }
        }
        __syncthreads();   // 1 wave: cheap lgkmcnt drain
        // ---- coalesced flush: 64 contiguous floats per env (s), 32 (r) ----
        for (int ee = 0; ee < EPB; ++ee) {
            const float v = sbuf[ee * SSTRIDE + tid];
            s_base[(size_t)(b0 + ee) * (2 * (T_STEPS + 1)) + chunk * 64 + 2 + tid] = v;
        }
        for (int ee = 0; ee < EPB; ee += 2) {
            const int e2i = ee + (tid >> 5);
            const int j   = tid & 31;
            const float v = rbuf[e2i * RSTRIDE + j];
            r_base[(size_t)(b0 + e2i) * (T_STEPS + 1) + chunk * 32 + 1 + j] = v;
        }
        __syncthreads();
    }
}

extern "C" void kernel_launch(void* const* d_in, const int* in_sizes, int n_in,
                              void* d_out, int out_size, void* d_ws, size_t ws_size,
                              hipStream_t stream) {
    const float* s0    = (const float*)d_in[0];
    const int*   act   = (const int*)d_in[1];
    const float* world = (const float*)d_in[2];
    float*       out   = (float*)d_out;
    uint32_t*    packed = (uint32_t*)d_ws;     // needs B*256*4 = 8 MiB

    const int B = in_sizes[0] / 2;             // 8192

    pack_kernel<<<B, 64, 0, stream>>>(world, packed);
    rollout_kernel<<<B / EPB, 64, 0, stream>>>(s0, act, packed, out, B);
}

// Round 11
// 429.358 us; speedup vs baseline: 1.1077x; 1.0176x over previous
//
#include <hip/hip_runtime.h>
#include <stdint.h>

#define T_STEPS 512
#define CELLS   4096            // 64*64
#define EPB     32              // envs per block (1 per lane, wave0 mirrored x2)
#define WPE     256             // packed world words per env (16 cells/word)
#define WPAD    257             // world LDS stride; word 256 = OOB sentinel (0)
#define ASTRIDE 132             // delta LDS stride: 128 words + pad to 16B mult
#define CHUNK   16              // steps per chunk (double-buffered flush)
#define NCHUNK  (T_STEPS / CHUNK)   // 32
#define KPC     (CHUNK / 4)         // 4 four-step k-iters per chunk
#define SSTRIDE 34              // s-buf stride: 16 steps * 2 + 2 (even)
#define RSTRIDE 18              // r-buf stride: 16 + 2 (even)

// ---- Kernel 1: pack world (float walls+goals) to 2-bit codes in d_ws ----
// code: 2 = goal (g==10, priority), 1 = wall (w==1 && !goal), 0 = free
__device__ __forceinline__ uint32_t code4(float4 w, float4 g) {
    uint32_t b0 = (g.x == 10.0f) ? 2u : ((w.x == 1.0f) ? 1u : 0u);
    uint32_t b1 = (g.y == 10.0f) ? 2u : ((w.y == 1.0f) ? 1u : 0u);
    uint32_t b2 = (g.z == 10.0f) ? 2u : ((w.z == 1.0f) ? 1u : 0u);
    uint32_t b3 = (g.w == 10.0f) ? 2u : ((w.w == 1.0f) ? 1u : 0u);
    return b0 | (b1 << 2) | (b2 << 4) | (b3 << 6);   // 4 cells x 2 bits
}

__global__ __launch_bounds__(64) void pack_kernel(
    const float* __restrict__ world, uint32_t* __restrict__ packed)
{
    const int b = blockIdx.x;
    const int t = threadIdx.x;
    const float* wbase = world + (size_t)b * (2 * CELLS);
    const float* gbase = wbase + CELLS;
    #pragma unroll
    for (int h = 0; h < 4; ++h) {
        const int w  = h * 64 + t;     // word index, 16 cells per word
        const int c0 = w * 16;
        uint32_t word = 0;
        #pragma unroll
        for (int j = 0; j < 4; ++j) {
            float4 wf = *(const float4*)(wbase + c0 + 4 * j);
            float4 gf = *(const float4*)(gbase + c0 + 4 * j);
            word |= code4(wf, gf) << (8 * j);
        }
        packed[(size_t)b * WPE + w] = word;
    }
}

// action -> flat delta e = dr*64 + dc, stored as int8
__device__ __forceinline__ int actdelta(int a) {
    return (a == 1) ? -64 : ((a == 2) ? 64 : ((a == 3) ? -1 : ((a == 4) ? 1 : 0)));
}

// ---- Kernel 2: producer/consumer rollout ----
// wave 0: per-lane rollout (env = tid&31, mirrored x2), writes LDS traj bufs
// wave 1: flushes previous chunk's buffers to global (coalesced), off-chain
__global__ __launch_bounds__(128) void rollout_kernel(
    const float* __restrict__ s0,
    const int*   __restrict__ act,
    const uint32_t* __restrict__ packed,
    float* __restrict__ out,
    int B)
{
    __shared__ uint32_t wlds[EPB * WPAD];         // 32896 B: 2-bit worlds
    __shared__ uint32_t alds[EPB * ASTRIDE];      // 16896 B: int8 step deltas
    __shared__ float    sbuf[2][EPB * SSTRIDE];   //  8704 B: dbuf s traj
    __shared__ float    rbuf[2][EPB * RSTRIDE];   //  4608 B: dbuf r traj
                                                  // total 63104 B

    const int tid = threadIdx.x;
    const int b0  = blockIdx.x * EPB;

    // ---- staging, 128 threads ----
    {   // worlds: 2048 uint4 loads (64 uint4 per env)
        const uint4* gw = (const uint4*)(packed + (size_t)b0 * WPE);
        #pragma unroll 4
        for (int it = 0; it < 16; ++it) {
            const int idx = it * 128 + tid;
            const uint4 v = gw[idx];
            const int env  = idx >> 6;
            const int base = env * WPAD + (idx & 63) * 4;
            wlds[base]     = v.x;
            wlds[base + 1] = v.y;
            wlds[base + 2] = v.z;
            wlds[base + 3] = v.w;
        }
    }
    if (tid < EPB) wlds[tid * WPAD + WPE] = 0u;   // OOB sentinel word = free
    {   // actions -> int8 deltas: 4096 words (128 per env)
        #pragma unroll 4
        for (int it = 0; it < 32; ++it) {
            const int widx = it * 128 + tid;
            const int env  = widx >> 7;
            const int w    = widx & 127;
            const int4 x = *(const int4*)(act + (size_t)(b0 + env) * T_STEPS + w * 4);
            const uint32_t dw = (uint32_t)(actdelta(x.x) & 255)
                              | ((uint32_t)(actdelta(x.y) & 255) << 8)
                              | ((uint32_t)(actdelta(x.z) & 255) << 16)
                              | ((uint32_t)(actdelta(x.w) & 255) << 24);
            alds[env * ASTRIDE + w] = dw;
        }
    }
    __syncthreads();

    float* const s_base = out;                                    // [B][513][2]
    float* const r_base = out + (size_t)B * (2 * (T_STEPS + 1));  // [B][513]

    if (tid < EPB) {   // t=0 outputs
        const float2 si = *(const float2*)(s0 + 2 * (size_t)(b0 + tid));
        *(float2*)(s_base + (size_t)(b0 + tid) * (2 * (T_STEPS + 1))) = si;
        r_base[(size_t)(b0 + tid) * (T_STEPS + 1)] = 0.0f;
    }

    // rollout state (used by wave 0 only; harmless for wave 1)
    const int e = tid & (EPB - 1);
    const float2 s = *(const float2*)(s0 + 2 * (size_t)(b0 + e));
    int c = (int)s.y;
    int p = ((int)s.x) * 64 + c;            // invariant: p == r*64 + c (exact)
    const uint32_t* myw = wlds + e * WPAD;
    const uint32_t* myd = alds + e * ASTRIDE;
    const int ft = tid - 64;                // flusher lane id

    // semantics (verified R3-R10, absmax 0): idx in [-4096,-1] wraps (+4096,
    // single NumPy normalization); all other OOB -> fill(NaN) -> free cell.
    auto waddr = [](int q) -> int {
        const int w = (int)((((unsigned)q) >> 4) & 255u);   // (q & 4095) >> 4
        return ((unsigned)(q + CELLS) < 2u * CELLS) ? w : WPE;
    };

    for (int chunk = 0; chunk < NCHUNK; ++chunk) {
        if (tid < 64) {
            // ---- producer: roll out 16 steps into buf[chunk&1] ----
            float* sb = &sbuf[chunk & 1][e * SSTRIDE];
            float* rb = &rbuf[chunk & 1][e * RSTRIDE];
            const uint4 awv = *(const uint4*)(myd + chunk * 4);  // 16 steps, 1 wait
            const uint32_t aws[4] = {awv.x, awv.y, awv.z, awv.w};
            #pragma unroll
            for (int k = 0; k < KPC; ++k) {
                const uint32_t aw = aws[k];
                const int e0 = (int)(aw << 24) >> 24;
                const int e1 = (int)(aw << 16) >> 24;
                const int e2 = (int)(aw << 8) >> 24;
                const int e3 = (int)aw >> 24;
                const int es[4] = {e0, e1, e2, e3};
                #pragma unroll
                for (int jj = 0; jj < 2; ++jj) {    // two 2-step rounds
                    const int ls = k * 4 + jj * 2;  // local step in chunk
                    const int ea = es[2 * jj];
                    const int eb = es[2 * jj + 1];
                    const int dca = ea * (ea & 1);  // col part: ±1 -> ±1 else 0
                    const int dcb = eb * (eb & 1);
                    const int q0  = p + ea;
                    const int q10 = p + eb;
                    const int q11 = q0 + eb;
                    const uint32_t w0  = myw[waddr(q0)];
                    const uint32_t w10 = myw[waddr(q10)];
                    const uint32_t w11 = myw[waddr(q11)];
                    // resolve step t (identical to verified R8/R10 logic)
                    const int l0 = (int)((w0 >> ((q0 & 15) << 1)) & 3);
                    const bool hw0 = (l0 == 1);
                    const float rew0 = (l0 == 2) ? 1.0f : (hw0 ? -1.0f : -0.01f);
                    const int p0 = hw0 ? p : q0;
                    const int c0 = hw0 ? c : c + dca;
                    // resolve step t+1 from matching speculative read
                    const uint32_t W1 = hw0 ? w10 : w11;
                    const int q1 = p0 + eb;
                    const int l1 = (int)((W1 >> ((q1 & 15) << 1)) & 3);
                    const bool hw1 = (l1 == 1);
                    const float rew1 = (l1 == 2) ? 1.0f : (hw1 ? -1.0f : -0.01f);
                    p = hw1 ? p0 : q1;
                    c = hw1 ? c0 : c0 + dcb;
                    const int r0i = (p0 - c0) >> 6;   // exact: p-c == 64*r
                    const int rfi = (p - c) >> 6;
                    *(float2*)(&sb[2 * ls])     = make_float2((float)r0i, (float)c0);
                    *(float2*)(&sb[2 * ls + 2]) = make_float2((float)rfi, (float)c);
                    *(float2*)(&rb[ls]) = make_float2(rew0, rew1);
                }
            }
        } else if (chunk > 0) {
            // ---- consumer: flush chunk-1's buffers (coalesced) ----
            const int ch  = chunk - 1;
            const int buf = ch & 1;
            #pragma unroll 4
            for (int ee0 = 0; ee0 < EPB; ee0 += 2) {       // s: 32 floats/env
                const int ee = ee0 + (ft >> 5);
                const int j  = ft & 31;
                const float v = sbuf[buf][ee * SSTRIDE + j];
                s_base[(size_t)(b0 + ee) * (2 * (T_STEPS + 1)) + ch * 32 + 2 + j] = v;
            }
            #pragma unroll 4
            for (int ee0 = 0; ee0 < EPB; ee0 += 4) {       // r: 16 floats/env
                const int ee = ee0 + (ft >> 4);
                const int j  = ft & 15;
                const float v = rbuf[buf][ee * RSTRIDE + j];
                r_base[(size_t)(b0 + ee) * (T_STEPS + 1) + ch * 16 + 1 + j] = v;
            }
        }
        __syncthreads();
    }
    if (tid >= 64) {   // final flush: chunk NCHUNK-1
        const int ch  = NCHUNK - 1;
        const int buf = ch & 1;
        #pragma unroll 4
        for (int ee0 = 0; ee0 < EPB; ee0 += 2) {
            const int ee = ee0 + (ft >> 5);
            const int j  = ft & 31;
            const float v = sbuf[buf][ee * SSTRIDE + j];
            s_base[(size_t)(b0 + ee) * (2 * (T_STEPS + 1)) + ch * 32 + 2 + j] = v;
        }
        #pragma unroll 4
        for (int ee0 = 0; ee0 < EPB; ee0 += 4) {
            const int ee = ee0 + (ft >> 4);
            const int j  = ft & 15;
            const float v = rbuf[buf][ee * RSTRIDE + j];
            r_base[(size_t)(b0 + ee) * (T_STEPS + 1) + ch * 16 + 1 + j] = v;
        }
    }
}

extern "C" void kernel_launch(void* const* d_in, const int* in_sizes, int n_in,
                              void* d_out, int out_size, void* d_ws, size_t ws_size,
                              hipStream_t stream) {
    const float* s0    = (const float*)d_in[0];
    const int*   act   = (const int*)d_in[1];
    const float* world = (const float*)d_in[2];
    float*       out   = (float*)d_out;
    uint32_t*    packed = (uint32_t*)d_ws;     // needs B*256*4 = 8 MiB

    const int B = in_sizes[0] / 2;             // 8192

    pack_kernel<<<B, 64, 0, stream>>>(world, packed);
    rollout_kernel<<<B / EPB, 128, 0, stream>>>(s0, act, packed, out, B);
}